// Round 6
// baseline (175.911 us; speedup 1.0000x reference)
//
#include <hip/hip_runtime.h>
#include <hip/hip_bf16.h>
#include <cstdint>
#include <cstddef>

#define TOK 8192
#define HID 1024
#define NE 8

typedef __bf16 bf16x4 __attribute__((ext_vector_type(4)));
typedef __bf16 bf16x8 __attribute__((ext_vector_type(8)));
typedef float floatx4 __attribute__((ext_vector_type(4)));

static __device__ __forceinline__ __bf16 f2bf(float x) {
    unsigned u = __builtin_bit_cast(unsigned, x);
    u += 0x7fffu + ((u >> 16) & 1u);   // RNE (inputs finite)
    unsigned short hs = (unsigned short)(u >> 16);
    return __builtin_bit_cast(__bf16, hs);
}

// ---------------- route: softmax top-1 + per-expert bucketing ----------------
__global__ void route_kernel(const float* __restrict__ gate, float* __restrict__ scale,
                             int* __restrict__ counts, int* __restrict__ list) {
    __shared__ int hcnt[NE];
    __shared__ int hbase[NE];
    const int t = threadIdx.x;
    if (t < NE) hcnt[t] = 0;
    __syncthreads();
    int tok = blockIdx.x * 256 + t;
    float g[NE];
#pragma unroll
    for (int j = 0; j < NE; j++) g[j] = gate[tok * NE + j];
    float gm = g[0]; int best = 0;
#pragma unroll
    for (int j = 1; j < NE; j++) {
        if (g[j] > gm) { gm = g[j]; best = j; }   // strict >: first-max (argmax)
    }
    float s = 0.f;
#pragma unroll
    for (int j = 0; j < NE; j++) s += __expf(g[j] - gm);
    scale[tok] = 1.0f / s;
    int lpos = atomicAdd(&hcnt[best], 1);
    __syncthreads();
    if (t < NE) hbase[t] = atomicAdd(&counts[t], hcnt[t]);
    __syncthreads();
    list[best * TOK + hbase[best] + lpos] = tok;
}

// ---------------- prep: fragment-linear operand construction ----------------
// Fragment layout (both operands): [group16][kc 0..31][lane 0..63][8 bf16], where for
// mfma_f32_16x16x32_bf16 lane=(ln + 16q) of group G holds row (G*16+ln), k = kc*32+q*8..+8.
// One (group,kc) cell = 1KB, written/read as lane-coalesced dwordx4.
//   blocks [0, 8192):     gather+convert X rows (routing order) -> Xg. Block (e,sg,kq)
//                         covers 32 slots x 256 k. Slots >= cnt (pad to 128) get zeros.
//   blocks [8192, 10240): W [E][K][N] -> Wf via 64x64 LDS transpose tile.
__global__ void prep_kernel(const float* __restrict__ X, const float* __restrict__ W,
                            const int* __restrict__ counts, const int* __restrict__ list,
                            __bf16* __restrict__ Xg, __bf16* __restrict__ Wf) {
    const int b = blockIdx.x;
    const int t = threadIdx.x;

    if (b < 8192) {
        // ---- X gather ----
        const int e  = b >> 10;
        const int rem = b & 1023;
        const int sg = rem >> 2;            // 32-slot group, 0..255
        const int kq = rem & 3;             // 256-k range
        const int cnt = counts[e];
        const int aligned = (cnt + 127) & ~127;
        if (sg * 32 >= aligned) return;

        int xb = 0;
#pragma unroll
        for (int j = 0; j < NE; j++) if (j < e) xb += (counts[j] + 127) & ~127;
        const int xb16 = xb >> 4;

        const int wave = t >> 6, lane = t & 63;
        const int ln = lane & 15, q = lane >> 4;
        const int ngl = wave & 1;
        const int slot = sg * 32 + ngl * 16 + ln;
        const bool v = (slot < cnt);
        const int tk = v ? list[e * TOK + slot] : 0;
        const float* rp = X + (size_t)tk * HID + q * 8;
        __bf16* dst = Xg + ((size_t)(xb16 + sg * 2 + ngl) * 32) * 512 + lane * 8;

#pragma unroll
        for (int c = 0; c < 4; c++) {
            const int kc = kq * 8 + (wave >> 1) * 4 + c;
            float4 x0 = make_float4(0.f, 0.f, 0.f, 0.f), x1 = x0;
            if (v) {
                x0 = *(const float4*)(rp + kc * 32);
                x1 = *(const float4*)(rp + kc * 32 + 4);
            }
            bf16x8 o;
            o[0] = f2bf(x0.x); o[1] = f2bf(x0.y); o[2] = f2bf(x0.z); o[3] = f2bf(x0.w);
            o[4] = f2bf(x1.x); o[5] = f2bf(x1.y); o[6] = f2bf(x1.z); o[7] = f2bf(x1.w);
            *(bf16x8*)(dst + (size_t)kc * 512) = o;
        }
    } else {
        // ---- W transpose: 64k x 64n tile through LDS ----
        const int bb = b - 8192;            // 0..2047
        const int e  = bb >> 8;
        const int kt = (bb >> 4) & 15;
        const int nt = bb & 15;
        const int k0 = kt * 64, n0 = nt * 64;

        __shared__ float ld[64][65];
        {
            const int r4 = t >> 4, c4 = t & 15;
#pragma unroll
            for (int i = 0; i < 4; i++) {
                int kl = r4 + 16 * i;
                float4 v = *(const float4*)(W + ((size_t)e * HID + (k0 + kl)) * HID + n0 + c4 * 4);
                ld[kl][c4 * 4 + 0] = v.x; ld[kl][c4 * 4 + 1] = v.y;
                ld[kl][c4 * 4 + 2] = v.z; ld[kl][c4 * 4 + 3] = v.w;
            }
        }
        __syncthreads();
        const int wave = t >> 6, lane = t & 63;
        const int ln = lane & 15, q = lane >> 4;
#pragma unroll
        for (int rep = 0; rep < 2; rep++) {
            const int fb = rep * 4 + wave;      // 0..7 = ngl(4) x kcl(2)
            const int ngl = fb & 3;
            const int kcl = fb >> 2;
            const int n = ngl * 16 + ln;
            bf16x8 o;
#pragma unroll
            for (int j = 0; j < 8; j++) o[j] = f2bf(ld[kcl * 32 + q * 8 + j][n]);
            const size_t grp = (size_t)(e * 64 + nt * 4 + ngl);
            *(bf16x8*)(Wf + (grp * 32 + kt * 2 + kcl) * 512 + lane * 8) = o;
        }
    }
}

// ---------------- barrier-free fragment-direct GEMM ----------------
// Block 128m x 128n, wave 64x64, 4x4 accs. All K-loop loads are lane-coalesced 1KB
// dwordx4 from fragment-linear Xg/Wf; 3-buffer register rotation (load kc+2 while
// MFMA on kc) keeps ~16 loads in flight with partial vmcnt waits — no LDS, no
// __syncthreads anywhere. Expert-per-XCD swizzle (bid%8==e) keeps the per-expert
// working set (Xg slice ~2.4MB + Wf slice 2MB) L2-resident.
__launch_bounds__(256)
__global__ void moe_gemm_bf16(const __bf16* __restrict__ Xg, const __bf16* __restrict__ Wf,
                              const float* __restrict__ Bias, const float* __restrict__ scale,
                              const int* __restrict__ counts, const int* __restrict__ list,
                              float* __restrict__ out) {
    const int bid = blockIdx.x;
    const int e  = bid & 7;
    const int mt = (bid >> 3) & 63;
    const int nt = bid >> 9;

    const int cnt = counts[e];
    if (mt * 128 >= cnt) return;
    const int n0 = nt * 128;

    int xb = 0;
#pragma unroll
    for (int j = 0; j < NE; j++) if (j < e) xb += (counts[j] + 127) & ~127;
    const int xb16 = xb >> 4;

    const int tid  = threadIdx.x;
    const int lane = tid & 63;
    const int wave = tid >> 6;
    const int ln = lane & 15;
    const int q  = lane >> 4;
    const int wm = (wave >> 1) * 64;
    const int wn = (wave & 1) * 64;

    const __bf16* aBase[4];
    const __bf16* bBase[4];
#pragma unroll
    for (int i = 0; i < 4; i++) {
        const size_t mgrp = (size_t)(xb16 + mt * 8 + (wm >> 4) + i);
        aBase[i] = Xg + mgrp * 16384 + lane * 8;
        const size_t ngrp = (size_t)(e * 64 + nt * 8 + (wn >> 4) + i);
        bBase[i] = Wf + ngrp * 16384 + lane * 8;
    }

    floatx4 acc[4][4];
#pragma unroll
    for (int mi = 0; mi < 4; mi++)
#pragma unroll
        for (int ni = 0; ni < 4; ni++) acc[mi][ni] = (floatx4){0.f, 0.f, 0.f, 0.f};

    bf16x8 af[3][4], bf[3][4];
#pragma unroll
    for (int s = 0; s < 2; s++)
#pragma unroll
        for (int i = 0; i < 4; i++) {
            af[s][i] = *(const bf16x8*)(aBase[i] + s * 512);
            bf[s][i] = *(const bf16x8*)(bBase[i] + s * 512);
        }

#pragma unroll
    for (int kc = 0; kc < 32; kc++) {
        const int cur = kc % 3;
        if (kc + 2 < 32) {
            const int nxt = (kc + 2) % 3;
#pragma unroll
            for (int i = 0; i < 4; i++) {
                af[nxt][i] = *(const bf16x8*)(aBase[i] + (kc + 2) * 512);
                bf[nxt][i] = *(const bf16x8*)(bBase[i] + (kc + 2) * 512);
            }
        }
#pragma unroll
        for (int mi = 0; mi < 4; mi++)
#pragma unroll
            for (int ni = 0; ni < 4; ni++)
                acc[mi][ni] = __builtin_amdgcn_mfma_f32_16x16x32_bf16(
                    af[cur][mi], bf[cur][ni], acc[mi][ni], 0, 0, 0);
    }

    float bn[4];
#pragma unroll
    for (int ni = 0; ni < 4; ni++) bn[ni] = Bias[e * HID + n0 + wn + ni * 16 + ln];

#pragma unroll
    for (int mi = 0; mi < 4; mi++) {
#pragma unroll
        for (int r = 0; r < 4; r++) {
            const int slot = mt * 128 + wm + mi * 16 + q * 4 + r;
            if (slot < cnt) {
                const int tk = list[e * TOK + slot];
                const float sc = scale[tk];
                const size_t ob = (size_t)tk * HID + n0 + wn + ln;
#pragma unroll
                for (int ni = 0; ni < 4; ni++)
                    __builtin_nontemporal_store(sc * (acc[mi][ni][r] + bn[ni]),
                                                &out[ob + ni * 16]);
            }
        }
    }
}

// ---------------- fallback (ws too small): direct fp32 reads, compile-time j ----------------
__launch_bounds__(256)
__global__ void moe_gemm_fb(const float* __restrict__ X, const float* __restrict__ W,
                            const float* __restrict__ Bias, const float* __restrict__ scale,
                            const int* __restrict__ counts, const int* __restrict__ list,
                            float* __restrict__ out) {
    const int bid = blockIdx.x;
    const int e  = bid >> 9;
    const int nt = (bid >> 6) & 7;
    const int mt = bid & 63;
    const int cnt = counts[e];
    if (mt * 128 >= cnt) return;
    const int mvalid = min(128, cnt - mt * 128);
    const int n0 = nt * 128;

    __shared__ __bf16 As[128 * 64];
    __shared__ __bf16 Bs[128 * 64];
    __shared__ int   tok[128];
    __shared__ float scl[128];

    const int tid = threadIdx.x;
    if (tid < 128) {
        int g = mt * 128 + tid;
        int tk = (g < cnt) ? list[e * TOK + g] : 0;
        tok[tid] = tk;
        scl[tid] = (g < cnt) ? scale[tk] : 0.f;
    }
    __syncthreads();

    const int c4 = tid & 15;
    const float* rp[8];
    bool rv[8];
#pragma unroll
    for (int i = 0; i < 8; i++) {
        int m = (tid >> 4) + 16 * i;
        rv[i] = (m < mvalid);
        rp[i] = X + (size_t)tok[m] * HID;
    }
    const int n4 = tid & 31;
    const int kb = tid >> 5;
    const float* wbase = W + (size_t)e * HID * HID + (size_t)(kb * 8) * HID + n0 + n4 * 4;

    const int lane = tid & 63;
    const int ln = lane & 15;
    const int q  = lane >> 4;
    const int wave = tid >> 6;
    const int wm = (wave >> 1) * 64;
    const int wn = (wave & 1) * 64;

    floatx4 acc[4][4];
#pragma unroll
    for (int mi = 0; mi < 4; mi++)
#pragma unroll
        for (int ni = 0; ni < 4; ni++) acc[mi][ni] = (floatx4){0.f, 0.f, 0.f, 0.f};

    for (int k0 = 0; k0 < HID; k0 += 64) {
#pragma unroll
        for (int i = 0; i < 8; i++) {
            int m = (tid >> 4) + 16 * i;
            float4 v = make_float4(0.f, 0.f, 0.f, 0.f);
            if (rv[i]) v = *(const float4*)(rp[i] + k0 + c4 * 4);
            bf16x4 b4;
            b4[0] = f2bf(v.x); b4[1] = f2bf(v.y); b4[2] = f2bf(v.z); b4[3] = f2bf(v.w);
            int chunk = c4 >> 1;
            int addr = m * 64 + ((chunk ^ (m & 7)) * 8) + (c4 & 1) * 4;
            *(bf16x4*)(&As[addr]) = b4;
        }
        {
            const float* wp = wbase + (size_t)k0 * HID;
            float4 rr[8];
#pragma unroll
            for (int r = 0; r < 8; r++) rr[r] = *(const float4*)(wp + (size_t)r * HID);
#pragma unroll
            for (int j = 0; j < 4; j++) {
                int n = n4 * 4 + j;
                int c = kb ^ (n & 7);
                bf16x8 pk;
                pk[0] = f2bf(j == 0 ? rr[0].x : j == 1 ? rr[0].y : j == 2 ? rr[0].z : rr[0].w);
                pk[1] = f2bf(j == 0 ? rr[1].x : j == 1 ? rr[1].y : j == 2 ? rr[1].z : rr[1].w);
                pk[2] = f2bf(j == 0 ? rr[2].x : j == 1 ? rr[2].y : j == 2 ? rr[2].z : rr[2].w);
                pk[3] = f2bf(j == 0 ? rr[3].x : j == 1 ? rr[3].y : j == 2 ? rr[3].z : rr[3].w);
                pk[4] = f2bf(j == 0 ? rr[4].x : j == 1 ? rr[4].y : j == 2 ? rr[4].z : rr[4].w);
                pk[5] = f2bf(j == 0 ? rr[5].x : j == 1 ? rr[5].y : j == 2 ? rr[5].z : rr[5].w);
                pk[6] = f2bf(j == 0 ? rr[6].x : j == 1 ? rr[6].y : j == 2 ? rr[6].z : rr[6].w);
                pk[7] = f2bf(j == 0 ? rr[7].x : j == 1 ? rr[7].y : j == 2 ? rr[7].z : rr[7].w);
                *(bf16x8*)(&Bs[n * 64 + c * 8]) = pk;
            }
        }
        __syncthreads();
#pragma unroll
        for (int kk = 0; kk < 64; kk += 32) {
            const int cbase = (kk >> 3) + q;
            bf16x8 af[4], bfv[4];
#pragma unroll
            for (int mi = 0; mi < 4; mi++) {
                int row = wm + mi * 16 + ln;
                af[mi] = *(const bf16x8*)(&As[row * 64 + ((cbase ^ (row & 7)) * 8)]);
            }
#pragma unroll
            for (int ni = 0; ni < 4; ni++) {
                int n = wn + ni * 16 + ln;
                bfv[ni] = *(const bf16x8*)(&Bs[n * 64 + ((cbase ^ (n & 7)) * 8)]);
            }
#pragma unroll
            for (int mi = 0; mi < 4; mi++)
#pragma unroll
                for (int ni = 0; ni < 4; ni++)
                    acc[mi][ni] = __builtin_amdgcn_mfma_f32_16x16x32_bf16(
                        af[mi], bfv[ni], acc[mi][ni], 0, 0, 0);
        }
        __syncthreads();
    }

    float bn[4];
#pragma unroll
    for (int ni = 0; ni < 4; ni++) bn[ni] = Bias[e * HID + n0 + wn + ni * 16 + ln];
#pragma unroll
    for (int mi = 0; mi < 4; mi++) {
#pragma unroll
        for (int r = 0; r < 4; r++) {
            int row = wm + mi * 16 + q * 4 + r;
            if (row < mvalid) {
                int t = tok[row];
                float sc = scl[row];
                size_t ob = (size_t)t * HID + n0 + wn + ln;
#pragma unroll
                for (int ni = 0; ni < 4; ni++)
                    out[ob + ni * 16] = sc * (acc[mi][ni][r] + bn[ni]);
            }
        }
    }
}

extern "C" void kernel_launch(void* const* d_in, const int* in_sizes, int n_in,
                              void* d_out, int out_size, void* d_ws, size_t ws_size,
                              hipStream_t stream) {
    const float* X    = (const float*)d_in[0];
    const float* G    = (const float*)d_in[1];
    const float* W    = (const float*)d_in[2];
    const float* Bias = (const float*)d_in[3];
    float* out = (float*)d_out;

    float* scale = (float*)d_ws;                                   // 32 KB
    int* counts  = (int*)((char*)d_ws + 32768);                    // 32 B (+pad)
    int* list    = (int*)((char*)d_ws + 36864);                    // 256 KB -> 299008
    __bf16* Xg   = (__bf16*)((char*)d_ws + 299008);                // 9216*2KB = 18 MB
    __bf16* Wf   = (__bf16*)((char*)d_ws + 299008 + 18874368);     // 16 MB
    const size_t need = 299008 + 18874368 + 16777216ULL;

    hipMemsetAsync(counts, 0, NE * sizeof(int), stream);

    if (ws_size >= need) {
        route_kernel<<<TOK / 256, 256, 0, stream>>>(G, scale, counts, list);
        prep_kernel<<<10240, 256, 0, stream>>>(X, W, counts, list, Xg, Wf);
        // grid: 8 nt x 64 mt x 8 e; e = bid%8 (expert-per-XCD); inactive m-tiles exit.
        moe_gemm_bf16<<<8 * 64 * 8, 256, 0, stream>>>(Xg, Wf, Bias, scale, counts, list, out);
    } else {
        route_kernel<<<TOK / 256, 256, 0, stream>>>(G, scale, counts, list);
        moe_gemm_fb<<<NE * 64 * 8, 256, 0, stream>>>(X, W, Bias, scale, counts, list, out);
    }
}

// Round 7
// 162.667 us; speedup vs baseline: 1.0814x; 1.0814x over previous
//
#include <hip/hip_runtime.h>
#include <hip/hip_bf16.h>
#include <cstdint>
#include <cstddef>

#define TOK 8192
#define HID 1024
#define NE 8

typedef __bf16 bf16x4 __attribute__((ext_vector_type(4)));
typedef __bf16 bf16x8 __attribute__((ext_vector_type(8)));
typedef float floatx4 __attribute__((ext_vector_type(4)));

static __device__ __forceinline__ __bf16 f2bf(float x) {
    unsigned u = __builtin_bit_cast(unsigned, x);
    u += 0x7fffu + ((u >> 16) & 1u);   // RNE (inputs finite)
    unsigned short hs = (unsigned short)(u >> 16);
    return __builtin_bit_cast(__bf16, hs);
}

// ---------------- route: softmax top-1 + per-expert bucketing ----------------
__global__ void route_kernel(const float* __restrict__ gate, float* __restrict__ scale,
                             int* __restrict__ counts, int* __restrict__ list) {
    __shared__ int hcnt[NE];
    __shared__ int hbase[NE];
    const int t = threadIdx.x;
    if (t < NE) hcnt[t] = 0;
    __syncthreads();
    int tok = blockIdx.x * 256 + t;
    float g[NE];
#pragma unroll
    for (int j = 0; j < NE; j++) g[j] = gate[tok * NE + j];
    float gm = g[0]; int best = 0;
#pragma unroll
    for (int j = 1; j < NE; j++) {
        if (g[j] > gm) { gm = g[j]; best = j; }   // strict >: first-max (argmax)
    }
    float s = 0.f;
#pragma unroll
    for (int j = 0; j < NE; j++) s += __expf(g[j] - gm);
    scale[tok] = 1.0f / s;
    int lpos = atomicAdd(&hcnt[best], 1);
    __syncthreads();
    if (t < NE) hbase[t] = atomicAdd(&counts[t], hcnt[t]);
    __syncthreads();
    list[best * TOK + hbase[best] + lpos] = tok;
}

// ---------------- prep: fragment-linear operand construction ----------------
// Layout (both operands): cell(group,kc) = 1KB at (group*32+kc)*512 elems; lane ln+16q
// of group G holds row G*16+ln, k = kc*32+q*8..+8, at byte offset lane*16 in the cell.
// All writes are 1KB lane-coalesced.
__global__ void prep_kernel(const float* __restrict__ X, const float* __restrict__ W,
                            const int* __restrict__ counts, const int* __restrict__ list,
                            __bf16* __restrict__ Xg, __bf16* __restrict__ Wf) {
    const int b = blockIdx.x;
    const int t = threadIdx.x;

    if (b < 8192) {
        // ---- X gather (routing order), zero-padded to 128-row multiples ----
        const int e  = b >> 10;
        const int rem = b & 1023;
        const int sg = rem >> 2;            // 32-slot group, 0..255
        const int kq = rem & 3;             // 256-k range
        const int cnt = counts[e];
        const int aligned = (cnt + 127) & ~127;
        if (sg * 32 >= aligned) return;

        int xb = 0;
#pragma unroll
        for (int j = 0; j < NE; j++) if (j < e) xb += (counts[j] + 127) & ~127;
        const int xb16 = xb >> 4;

        const int wave = t >> 6, lane = t & 63;
        const int ln = lane & 15, q = lane >> 4;
        const int ngl = wave & 1;
        const int slot = sg * 32 + ngl * 16 + ln;
        const bool v = (slot < cnt);
        const int tk = v ? list[e * TOK + slot] : 0;
        const float* rp = X + (size_t)tk * HID + q * 8;
        __bf16* dst = Xg + ((size_t)(xb16 + sg * 2 + ngl) * 32) * 512 + lane * 8;

#pragma unroll
        for (int c = 0; c < 4; c++) {
            const int kc = kq * 8 + (wave >> 1) * 4 + c;
            float4 x0 = make_float4(0.f, 0.f, 0.f, 0.f), x1 = x0;
            if (v) {
                x0 = *(const float4*)(rp + kc * 32);
                x1 = *(const float4*)(rp + kc * 32 + 4);
            }
            bf16x8 o;
            o[0] = f2bf(x0.x); o[1] = f2bf(x0.y); o[2] = f2bf(x0.z); o[3] = f2bf(x0.w);
            o[4] = f2bf(x1.x); o[5] = f2bf(x1.y); o[6] = f2bf(x1.z); o[7] = f2bf(x1.w);
            *(bf16x8*)(dst + (size_t)kc * 512) = o;
        }
    } else {
        // ---- W transpose: 64k x 64n tile through LDS, fragment-linear output ----
        const int bb = b - 8192;            // 0..2047
        const int e  = bb >> 8;
        const int kt = (bb >> 4) & 15;
        const int nt = bb & 15;
        const int k0 = kt * 64, n0 = nt * 64;

        __shared__ float ld[64][65];
        {
            const int r4 = t >> 4, c4 = t & 15;
#pragma unroll
            for (int i = 0; i < 4; i++) {
                int kl = r4 + 16 * i;
                float4 v = *(const float4*)(W + ((size_t)e * HID + (k0 + kl)) * HID + n0 + c4 * 4);
                ld[kl][c4 * 4 + 0] = v.x; ld[kl][c4 * 4 + 1] = v.y;
                ld[kl][c4 * 4 + 2] = v.z; ld[kl][c4 * 4 + 3] = v.w;
            }
        }
        __syncthreads();
        const int wave = t >> 6, lane = t & 63;
        const int ln = lane & 15, q = lane >> 4;
#pragma unroll
        for (int rep = 0; rep < 2; rep++) {
            const int fb = rep * 4 + wave;      // 0..7 = ngl(4) x kcl(2)
            const int ngl = fb & 3;
            const int kcl = fb >> 2;
            const int n = ngl * 16 + ln;
            bf16x8 o;
#pragma unroll
            for (int j = 0; j < 8; j++) o[j] = f2bf(ld[kcl * 32 + q * 8 + j][n]);
            const size_t grp = (size_t)(e * 64 + nt * 4 + ngl);
            *(bf16x8*)(Wf + (grp * 32 + kt * 2 + kcl) * 512 + lane * 8) = o;
        }
    }
}

// ---------------- GEMM: 128x128 tiles, fragment-linear LDS staging ----------------
// Per K-iter (64k) the block stages 16 A-cells + 16 B-cells (1KB each, lane-coalesced
// global_load_lds_dwordx4 from fragment-linear Xg/Wf — channel-balanced contiguous
// requests, the m97-style pattern). LDS is fragment-linear too: ds_read_b128 at
// cell+lane*16 is conflict-free by construction. Double-buffered (64KB, 2 blocks/CU),
// one barrier per iter, stage(k+1) issued before compute(k). Expert-per-XCD swizzle
// (bid%8==e) keeps each expert's Xg slice (~2.3MB) + Wf (2MB) near-L2-resident.
__launch_bounds__(256)
__global__ void moe_gemm_bf16(const __bf16* __restrict__ Xg, const __bf16* __restrict__ Wf,
                              const float* __restrict__ Bias, const float* __restrict__ scale,
                              const int* __restrict__ counts, const int* __restrict__ list,
                              float* __restrict__ out) {
    const int bid = blockIdx.x;
    const int e  = bid & 7;
    const int mt = (bid >> 3) & 63;
    const int nt = bid >> 9;

    const int cnt = counts[e];
    if (mt * 128 >= cnt) return;
    const int n0 = nt * 128;

    int xb = 0;
#pragma unroll
    for (int j = 0; j < NE; j++) if (j < e) xb += (counts[j] + 127) & ~127;
    const int mgrpb = (xb >> 4) + mt * 8;     // first of 8 m-groups
    const int ngrpb = e * 64 + nt * 8;        // first of 8 n-groups

    __shared__ __bf16 As[2][8192];
    __shared__ __bf16 Bs[2][8192];

    const int tid  = threadIdx.x;
    const int lane = tid & 63;
    const int wave = tid >> 6;
    const int ln = lane & 15;
    const int q  = lane >> 4;

    // Staging: wave w covers cell indices w*4..w*4+3; cell idx = gi*2 + kcl.
    const __bf16* asrc[4];
    const __bf16* bsrc[4];
#pragma unroll
    for (int c = 0; c < 4; c++) {
        const int gi  = wave * 2 + (c >> 1);
        const int kcl = c & 1;
        asrc[c] = Xg + (size_t)(mgrpb + gi) * 16384 + kcl * 512 + lane * 8;
        bsrc[c] = Wf + (size_t)(ngrpb + gi) * 16384 + kcl * 512 + lane * 8;
    }

    auto stage = [&](int kt, int buf) {
        const int koff = kt * 1024;           // kt*2 kc-cells * 512
#pragma unroll
        for (int c = 0; c < 4; c++) {
            __builtin_amdgcn_global_load_lds(
                (const __attribute__((address_space(1))) void*)(asrc[c] + koff),
                (__attribute__((address_space(3))) void*)(&As[buf][(wave * 4 + c) * 512]),
                16, 0, 0);
            __builtin_amdgcn_global_load_lds(
                (const __attribute__((address_space(1))) void*)(bsrc[c] + koff),
                (__attribute__((address_space(3))) void*)(&Bs[buf][(wave * 4 + c) * 512]),
                16, 0, 0);
        }
    };

    floatx4 acc[4][4];
#pragma unroll
    for (int mi = 0; mi < 4; mi++)
#pragma unroll
        for (int ni = 0; ni < 4; ni++) acc[mi][ni] = (floatx4){0.f, 0.f, 0.f, 0.f};

    const int wmg = (wave >> 1) * 4;          // wave's first m-group (local)
    const int wng = (wave & 1) * 4;           // wave's first n-group (local)

    stage(0, 0);
    for (int kt = 0; kt < 16; ++kt) {
        __syncthreads();                      // buf[kt&1] ready
        if (kt < 15) stage(kt + 1, (kt + 1) & 1);
        const int buf = kt & 1;

#pragma unroll
        for (int kcl = 0; kcl < 2; kcl++) {
            bf16x8 af[4], bfv[4];
#pragma unroll
            for (int mi = 0; mi < 4; mi++)
                af[mi] = *(const bf16x8*)(&As[buf][((wmg + mi) * 2 + kcl) * 512 + lane * 8]);
#pragma unroll
            for (int ni = 0; ni < 4; ni++)
                bfv[ni] = *(const bf16x8*)(&Bs[buf][((wng + ni) * 2 + kcl) * 512 + lane * 8]);
#pragma unroll
            for (int mi = 0; mi < 4; mi++)
#pragma unroll
                for (int ni = 0; ni < 4; ni++)
                    acc[mi][ni] = __builtin_amdgcn_mfma_f32_16x16x32_bf16(
                        af[mi], bfv[ni], acc[mi][ni], 0, 0, 0);
        }
    }

    const int wm = (wave >> 1) * 64;
    const int wn = (wave & 1) * 64;
    float bn[4];
#pragma unroll
    for (int ni = 0; ni < 4; ni++) bn[ni] = Bias[e * HID + n0 + wn + ni * 16 + ln];

#pragma unroll
    for (int mi = 0; mi < 4; mi++) {
#pragma unroll
        for (int r = 0; r < 4; r++) {
            const int slot = mt * 128 + wm + mi * 16 + q * 4 + r;
            if (slot < cnt) {
                const int tk = list[e * TOK + slot];
                const float sc = scale[tk];
                const size_t ob = (size_t)tk * HID + n0 + wn + ln;
#pragma unroll
                for (int ni = 0; ni < 4; ni++)
                    __builtin_nontemporal_store(sc * (acc[mi][ni][r] + bn[ni]),
                                                &out[ob + ni * 16]);
            }
        }
    }
}

// ---------------- fallback (ws too small): direct fp32 reads, compile-time j ----------------
__launch_bounds__(256)
__global__ void moe_gemm_fb(const float* __restrict__ X, const float* __restrict__ W,
                            const float* __restrict__ Bias, const float* __restrict__ scale,
                            const int* __restrict__ counts, const int* __restrict__ list,
                            float* __restrict__ out) {
    const int bid = blockIdx.x;
    const int e  = bid >> 9;
    const int nt = (bid >> 6) & 7;
    const int mt = bid & 63;
    const int cnt = counts[e];
    if (mt * 128 >= cnt) return;
    const int mvalid = min(128, cnt - mt * 128);
    const int n0 = nt * 128;

    __shared__ __bf16 As[128 * 64];
    __shared__ __bf16 Bs[128 * 64];
    __shared__ int   tok[128];
    __shared__ float scl[128];

    const int tid = threadIdx.x;
    if (tid < 128) {
        int g = mt * 128 + tid;
        int tk = (g < cnt) ? list[e * TOK + g] : 0;
        tok[tid] = tk;
        scl[tid] = (g < cnt) ? scale[tk] : 0.f;
    }
    __syncthreads();

    const int c4 = tid & 15;
    const float* rp[8];
    bool rv[8];
#pragma unroll
    for (int i = 0; i < 8; i++) {
        int m = (tid >> 4) + 16 * i;
        rv[i] = (m < mvalid);
        rp[i] = X + (size_t)tok[m] * HID;
    }
    const int n4 = tid & 31;
    const int kb = tid >> 5;
    const float* wbase = W + (size_t)e * HID * HID + (size_t)(kb * 8) * HID + n0 + n4 * 4;

    const int lane = tid & 63;
    const int ln = lane & 15;
    const int q  = lane >> 4;
    const int wave = tid >> 6;
    const int wm = (wave >> 1) * 64;
    const int wn = (wave & 1) * 64;

    floatx4 acc[4][4];
#pragma unroll
    for (int mi = 0; mi < 4; mi++)
#pragma unroll
        for (int ni = 0; ni < 4; ni++) acc[mi][ni] = (floatx4){0.f, 0.f, 0.f, 0.f};

    for (int k0 = 0; k0 < HID; k0 += 64) {
#pragma unroll
        for (int i = 0; i < 8; i++) {
            int m = (tid >> 4) + 16 * i;
            float4 v = make_float4(0.f, 0.f, 0.f, 0.f);
            if (rv[i]) v = *(const float4*)(rp[i] + k0 + c4 * 4);
            bf16x4 b4;
            b4[0] = f2bf(v.x); b4[1] = f2bf(v.y); b4[2] = f2bf(v.z); b4[3] = f2bf(v.w);
            int chunk = c4 >> 1;
            int addr = m * 64 + ((chunk ^ (m & 7)) * 8) + (c4 & 1) * 4;
            *(bf16x4*)(&As[addr]) = b4;
        }
        {
            const float* wp = wbase + (size_t)k0 * HID;
            float4 rr[8];
#pragma unroll
            for (int r = 0; r < 8; r++) rr[r] = *(const float4*)(wp + (size_t)r * HID);
#pragma unroll
            for (int j = 0; j < 4; j++) {
                int n = n4 * 4 + j;
                int c = kb ^ (n & 7);
                bf16x8 pk;
                pk[0] = f2bf(j == 0 ? rr[0].x : j == 1 ? rr[0].y : j == 2 ? rr[0].z : rr[0].w);
                pk[1] = f2bf(j == 0 ? rr[1].x : j == 1 ? rr[1].y : j == 2 ? rr[1].z : rr[1].w);
                pk[2] = f2bf(j == 0 ? rr[2].x : j == 1 ? rr[2].y : j == 2 ? rr[2].z : rr[2].w);
                pk[3] = f2bf(j == 0 ? rr[3].x : j == 1 ? rr[3].y : j == 2 ? rr[3].z : rr[3].w);
                pk[4] = f2bf(j == 0 ? rr[4].x : j == 1 ? rr[4].y : j == 2 ? rr[4].z : rr[4].w);
                pk[5] = f2bf(j == 0 ? rr[5].x : j == 1 ? rr[5].y : j == 2 ? rr[5].z : rr[5].w);
                pk[6] = f2bf(j == 0 ? rr[6].x : j == 1 ? rr[6].y : j == 2 ? rr[6].z : rr[6].w);
                pk[7] = f2bf(j == 0 ? rr[7].x : j == 1 ? rr[7].y : j == 2 ? rr[7].z : rr[7].w);
                *(bf16x8*)(&Bs[n * 64 + c * 8]) = pk;
            }
        }
        __syncthreads();
#pragma unroll
        for (int kk = 0; kk < 64; kk += 32) {
            const int cbase = (kk >> 3) + q;
            bf16x8 af[4], bfv[4];
#pragma unroll
            for (int mi = 0; mi < 4; mi++) {
                int row = wm + mi * 16 + ln;
                af[mi] = *(const bf16x8*)(&As[row * 64 + ((cbase ^ (row & 7)) * 8)]);
            }
#pragma unroll
            for (int ni = 0; ni < 4; ni++) {
                int n = wn + ni * 16 + ln;
                bfv[ni] = *(const bf16x8*)(&Bs[n * 64 + ((cbase ^ (n & 7)) * 8)]);
            }
#pragma unroll
            for (int mi = 0; mi < 4; mi++)
#pragma unroll
                for (int ni = 0; ni < 4; ni++)
                    acc[mi][ni] = __builtin_amdgcn_mfma_f32_16x16x32_bf16(
                        af[mi], bfv[ni], acc[mi][ni], 0, 0, 0);
        }
        __syncthreads();
    }

    float bn[4];
#pragma unroll
    for (int ni = 0; ni < 4; ni++) bn[ni] = Bias[e * HID + n0 + wn + ni * 16 + ln];
#pragma unroll
    for (int mi = 0; mi < 4; mi++) {
#pragma unroll
        for (int r = 0; r < 4; r++) {
            int row = wm + mi * 16 + q * 4 + r;
            if (row < mvalid) {
                int t = tok[row];
                float sc = scl[row];
                size_t ob = (size_t)t * HID + n0 + wn + ln;
#pragma unroll
                for (int ni = 0; ni < 4; ni++)
                    out[ob + ni * 16] = sc * (acc[mi][ni][r] + bn[ni]);
            }
        }
    }
}

extern "C" void kernel_launch(void* const* d_in, const int* in_sizes, int n_in,
                              void* d_out, int out_size, void* d_ws, size_t ws_size,
                              hipStream_t stream) {
    const float* X    = (const float*)d_in[0];
    const float* G    = (const float*)d_in[1];
    const float* W    = (const float*)d_in[2];
    const float* Bias = (const float*)d_in[3];
    float* out = (float*)d_out;

    float* scale = (float*)d_ws;                                   // 32 KB
    int* counts  = (int*)((char*)d_ws + 32768);                    // 32 B (+pad)
    int* list    = (int*)((char*)d_ws + 36864);                    // 256 KB -> 299008
    __bf16* Xg   = (__bf16*)((char*)d_ws + 299008);                // 18 MB (frag-linear)
    __bf16* Wf   = (__bf16*)((char*)d_ws + 299008 + 18874368);     // 16 MB (frag-linear)
    const size_t need = 299008 + 18874368 + 16777216ULL;

    hipMemsetAsync(counts, 0, NE * sizeof(int), stream);

    if (ws_size >= need) {
        route_kernel<<<TOK / 256, 256, 0, stream>>>(G, scale, counts, list);
        prep_kernel<<<10240, 256, 0, stream>>>(X, W, counts, list, Xg, Wf);
        // grid: 8 nt x 64 mt x 8 e; e = bid%8 (expert-per-XCD); inactive m-tiles exit.
        moe_gemm_bf16<<<8 * 64 * 8, 256, 0, stream>>>(Xg, Wf, Bias, scale, counts, list, out);
    } else {
        route_kernel<<<TOK / 256, 256, 0, stream>>>(G, scale, counts, list);
        moe_gemm_fb<<<NE * 64 * 8, 256, 0, stream>>>(X, W, Bias, scale, counts, list, out);
    }
}